// Round 10
// baseline (286.849 us; speedup 1.0000x reference)
//
#include <hip/hip_runtime.h>
#include <hip/hip_bf16.h>
#include <hip/hip_fp8.h>
#include <stdint.h>

#define Nn 8192
#define TWO_N 16384
#define INV_TAU 2.0f

typedef unsigned short u16;
typedef unsigned char u8;
typedef __bf16 bf16x8 __attribute__((ext_vector_type(8)));
typedef float f32x4 __attribute__((ext_vector_type(4)));
typedef int i32x8 __attribute__((ext_vector_type(8)));

typedef const __attribute__((address_space(1))) void* gas_ptr;
typedef __attribute__((address_space(3))) void* las_ptr;

__device__ __forceinline__ void async_copy16(const void* g, void* l) {
  __builtin_amdgcn_global_load_lds((gas_ptr)g, (las_ptr)l, 16, 0, 0);
}

__device__ __forceinline__ u16 f2bf(float x) {
  uint32_t u = __float_as_uint(x);
  u = u + 0x7fffu + ((u >> 16) & 1u);
  return (u16)(u >> 16);
}

// ---------------- W fp32 -> bf16 pre-cast (both layers) ----------------------
__global__ void wcast(const float* __restrict__ W1, const float* __restrict__ W2,
                      u16* __restrict__ W1b, u16* __restrict__ W2b) {
  int i = blockIdx.x * 256 + threadIdx.x;   // 16384 quads per array
  float4 a = ((const float4*)W1)[i];
  ushort4 o1; o1.x = f2bf(a.x); o1.y = f2bf(a.y); o1.z = f2bf(a.z); o1.w = f2bf(a.w);
  ((ushort4*)W1b)[i] = o1;
  float4 b = ((const float4*)W2)[i];
  ushort4 o2; o2.x = f2bf(b.x); o2.y = f2bf(b.y); o2.z = f2bf(b.z); o2.w = f2bf(b.w);
  ((ushort4*)W2b)[i] = o2;
}

// ---------------- fused MLP + normalize + fp8 emit ---------------------------
// 256 blocks x 64 rows. W chunks (32KB bf16) flow via global_load_lds into a
// 2-buffer pipeline (prefetch-behind-barrier). H1 lives in LDS only.
__global__ __launch_bounds__(256)
void mlp_norm(const float* __restrict__ z1, const float* __restrict__ z2,
              const u16* __restrict__ W1b, const float* __restrict__ b1,
              const u16* __restrict__ W2b, const float* __restrict__ b2,
              u8* __restrict__ Mf8, float* __restrict__ snorm,
              float* __restrict__ rsum) {
  __shared__ __bf16 sZ[64 * 64];       // 8 KB  (layer1 A; reduce scratch later)
  __shared__ __bf16 sW[2][256 * 64];   // 2 x 32 KB (W chunk dbuf)
  __shared__ __bf16 sH[64 * 256];      // 32 KB (H1 full-K)
  const int bx = blockIdx.x;
  const int i0 = bx * 64;
  const float* Zsrc = (bx < 128) ? (z1 + (size_t)i0 * 256)
                                 : (z2 + (size_t)(i0 - Nn) * 256);
  const int t = threadIdx.x;
  const int lane = t & 63, wave = t >> 6;
  const int wn = wave * 64;
  const int fr = lane >> 4, fc = lane & 15;
  const int sw = fc & 7;

  if (t < 64) rsum[i0 + t] = 0.f;

  f32x4 acc[4][4];
#pragma unroll
  for (int a = 0; a < 4; a++)
#pragma unroll
    for (int b = 0; b < 4; b++) acc[a][b] = (f32x4){0.f, 0.f, 0.f, 0.f};

  // issue W chunk 0 (W1, k0=0)
#pragma unroll
  for (int it = 0; it < 8; ++it) {
    int c = t + 256 * it;
    int row = c >> 3, g = (c & 7) ^ (row & 7);
    async_copy16(W1b + (size_t)row * 256 + g * 8, (void*)&sW[0][c * 8]);
  }

  // ---- layer 1 (chunks 0..3) ----
  for (int cc = 0; cc < 4; ++cc) {
    const int k0 = cc * 64;
    __syncthreads();               // drains W(cc); prev buffers free
    // stage Z chunk inline (fp32 -> bf16)
#pragma unroll
    for (int it = 0; it < 2; ++it) {
      int c = t + 256 * it;
      int row = c >> 3, g = (c & 7) ^ (row & 7);
      const float* s = Zsrc + (size_t)row * 256 + k0 + g * 8;
      float4 a0 = *(const float4*)s, a1 = *(const float4*)(s + 4);
      bf16x8 v = {(__bf16)a0.x, (__bf16)a0.y, (__bf16)a0.z, (__bf16)a0.w,
                  (__bf16)a1.x, (__bf16)a1.y, (__bf16)a1.z, (__bf16)a1.w};
      *(bf16x8*)&sZ[c * 8] = v;
    }
    __syncthreads();               // Z visible; no outstanding async here
    // prefetch W(cc+1) behind the barrier
    {
      int nc = cc + 1;
      const u16* Wsrc = (nc < 4) ? W1b : W2b;
      int nk0 = (nc & 3) * 64;
      u16* dst = (u16*)&sW[nc & 1][0];
#pragma unroll
      for (int it = 0; it < 8; ++it) {
        int c = t + 256 * it;
        int row = c >> 3, g = (c & 7) ^ (row & 7);
        async_copy16(Wsrc + (size_t)row * 256 + nk0 + g * 8, (void*)&dst[c * 8]);
      }
    }
    const __bf16* sWc = &sW[cc & 1][0];
#pragma unroll
    for (int ks = 0; ks < 2; ++ks) {
      bf16x8 af[4], bfr[4];
#pragma unroll
      for (int mi = 0; mi < 4; mi++)
        af[mi] = *(const bf16x8*)&sZ[(mi * 16 + fc) * 64 + (((ks * 4 + fr) ^ sw) * 8)];
#pragma unroll
      for (int ni = 0; ni < 4; ni++)
        bfr[ni] = *(const bf16x8*)&sWc[(wn + ni * 16 + fc) * 64 + (((ks * 4 + fr) ^ sw) * 8)];
#pragma unroll
      for (int mi = 0; mi < 4; mi++)
#pragma unroll
        for (int ni = 0; ni < 4; ni++)
          acc[mi][ni] = __builtin_amdgcn_mfma_f32_16x16x32_bf16(af[mi], bfr[ni], acc[mi][ni], 0, 0, 0);
    }
  }

  // layer-1 epilogue: bias + elu -> bf16 into sH (granule-xor swizzled rows)
  {
    float bv[4];
#pragma unroll
    for (int ni = 0; ni < 4; ni++) bv[ni] = b1[wn + ni * 16 + fc];
#pragma unroll
    for (int mi = 0; mi < 4; mi++)
#pragma unroll
      for (int ni = 0; ni < 4; ni++) {
        int col = wn + ni * 16 + fc;
        int gc = col >> 3;
#pragma unroll
        for (int r = 0; r < 4; r++) {
          int row = mi * 16 + fr * 4 + r;
          float v = acc[mi][ni][r] + bv[ni];
          v = v > 0.f ? v : (__expf(v) - 1.f);
          int pos = (gc & 24) | ((gc & 7) ^ (row & 7));
          sH[row * 256 + pos * 8 + (col & 7)] = (__bf16)v;
          acc[mi][ni][r] = 0.f;
        }
      }
  }

  // ---- layer 2 (chunks 4..7; A = sH resident) ----
  for (int cc = 4; cc < 8; ++cc) {
    const int k0 = (cc & 3) * 64;
    __syncthreads();               // drains W(cc) + (first iter) sH writes
    if (cc + 1 < 8) {              // prefetch W(cc+1) behind the barrier
      int nc = cc + 1;
      int nk0 = (nc & 3) * 64;
      u16* dst = (u16*)&sW[nc & 1][0];
#pragma unroll
      for (int it = 0; it < 8; ++it) {
        int c = t + 256 * it;
        int row = c >> 3, g = (c & 7) ^ (row & 7);
        async_copy16(W2b + (size_t)row * 256 + nk0 + g * 8, (void*)&dst[c * 8]);
      }
    }
    const __bf16* sWc = &sW[cc & 1][0];
    const int kgb = k0 >> 3;
#pragma unroll
    for (int ks = 0; ks < 2; ++ks) {
      bf16x8 af[4], bfr[4];
#pragma unroll
      for (int mi = 0; mi < 4; mi++)
        af[mi] = *(const bf16x8*)&sH[(mi * 16 + fc) * 256 + (kgb + (((ks * 4 + fr) ^ sw))) * 8];
#pragma unroll
      for (int ni = 0; ni < 4; ni++)
        bfr[ni] = *(const bf16x8*)&sWc[(wn + ni * 16 + fc) * 64 + (((ks * 4 + fr) ^ sw) * 8)];
#pragma unroll
      for (int mi = 0; mi < 4; mi++)
#pragma unroll
        for (int ni = 0; ni < 4; ni++)
          acc[mi][ni] = __builtin_amdgcn_mfma_f32_16x16x32_bf16(af[mi], bfr[ni], acc[mi][ni], 0, 0, 0);
    }
  }

  // ---- epilogue: bias, cross-wave row-norm, fp8 emit, snorm ----
  float bv[4];
#pragma unroll
  for (int ni = 0; ni < 4; ni++) bv[ni] = b2[wn + ni * 16 + fc];

  __syncthreads();                 // sZ dead; reuse as reduce scratch
  float* red = (float*)sZ;         // [64 rows][4 waves]
  float* red2 = red + 256;

#pragma unroll
  for (int mi = 0; mi < 4; mi++) {
    float ssq[4] = {0.f, 0.f, 0.f, 0.f};
#pragma unroll
    for (int ni = 0; ni < 4; ni++)
#pragma unroll
      for (int r = 0; r < 4; r++) {
        float v = acc[mi][ni][r] + bv[ni];
        acc[mi][ni][r] = v;
        ssq[r] += v * v;
      }
#pragma unroll
    for (int r = 0; r < 4; r++) {
      float v = ssq[r];
#pragma unroll
      for (int off = 1; off < 16; off <<= 1) v += __shfl_xor(v, off, 16);
      if (fc == 0) red[(mi * 16 + fr * 4 + r) * 4 + wave] = v;
    }
  }
  __syncthreads();

#pragma unroll
  for (int mi = 0; mi < 4; mi++) {
    float ssq2[4] = {0.f, 0.f, 0.f, 0.f};
#pragma unroll
    for (int r = 0; r < 4; r++) {
      int row = mi * 16 + fr * 4 + r;
      float ss = red[row * 4] + red[row * 4 + 1] + red[row * 4 + 2] + red[row * 4 + 3];
      float rn = 1.f / fmaxf(sqrtf(ss), 1e-12f);
#pragma unroll
      for (int ni = 0; ni < 4; ni++) {
        float v = acc[mi][ni][r] * rn;
        __hip_fp8_e4m3 q(v);
        Mf8[(size_t)(i0 + row) * 256 + wn + ni * 16 + fc] = q.__x;
        float fv = (float)q;
        ssq2[r] += fv * fv;
      }
    }
#pragma unroll
    for (int r = 0; r < 4; r++) {
      float v = ssq2[r];
#pragma unroll
      for (int off = 1; off < 16; off <<= 1) v += __shfl_xor(v, off, 16);
      if (fc == 0) red2[(mi * 16 + fr * 4 + r) * 4 + wave] = v;
    }
  }
  __syncthreads();
  if (t < 64)
    snorm[i0 + t] = red2[t * 4] + red2[t * 4 + 1] + red2[t * 4 + 2] + red2[t * 4 + 3];
}

// ---------------- symmetric Gram, MX fp8 K=128, A-in-regs, 16KB B chunks -----
// 2 x 16 KB B dbuf (32 KB LDS) -> 4 blocks/CU. Chunk cc = half-K of tile
// jt0 + (cc>>1); prefetch-behind-barrier; epilogue on odd cc.
__global__ __launch_bounds__(256, 4)
void gram_sym(const u8* __restrict__ Mf8, float* __restrict__ rsum) {
  __shared__ u8 sB8[2][128 * 128];   // 2 x 16 KB
  const int t = threadIdx.x;
  const int lane = t & 63, wave = t >> 6;
  const int wm = (wave >> 1) * 64, wn = (wave & 1) * 64;
  const int fr = lane >> 4, fc = lane & 15;

  // ---- strip mapping (band closed form), long strips dispatched first ----
  int f = 2111 - blockIdx.x;
  int b = 0;
  while (f >= 2 * (b + 1) * (b + 2)) ++b;
  int rem = f - 2 * b * (b + 1);
  int r = rem / (b + 1);
  int q = rem - r * (b + 1);
  int k = 4 * b + 1 + r;
  const int i_t = 128 - k;
  const int jt0 = i_t + 4 * q;
  const int L = min(4, k - 4 * q);
  const int i0 = i_t * 128;

  // stage B chunk 0 (tile jt0, low half-K) into buffer 0
  {
    const u8* Bg = Mf8 + (size_t)jt0 * 128 * 256;
#pragma unroll
    for (int it = 0; it < 4; ++it) {
      int c = t + 256 * it;
      int row = c >> 3, slot = c & 7;
      int g = slot ^ (row & 7);
      async_copy16(Bg + (size_t)row * 256 + g * 16, (void*)&sB8[0][c * 16]);
    }
  }

  // gather A fragments into registers (L2-resident; once per strip)
  i32x8 afr[4][2];
  {
    const u8* Ag = Mf8 + (size_t)i0 * 256;
#pragma unroll
    for (int mi = 0; mi < 4; ++mi) {
      const u8* rp = Ag + (size_t)(wm + mi * 16 + fc) * 256 + fr * 32;
#pragma unroll
      for (int kb = 0; kb < 2; ++kb) {
        int4 lo = *(const int4*)(rp + kb * 128);
        int4 hi = *(const int4*)(rp + kb * 128 + 16);
        afr[mi][kb] = (i32x8){lo.x, lo.y, lo.z, lo.w, hi.x, hi.y, hi.z, hi.w};
      }
    }
  }

  float rowacc[4][4];
#pragma unroll
  for (int a = 0; a < 4; a++)
#pragma unroll
    for (int rr = 0; rr < 4; rr++) rowacc[a][rr] = 0.f;

  f32x4 acc[4][4];
#pragma unroll
  for (int a = 0; a < 4; a++)
#pragma unroll
    for (int bb = 0; bb < 4; bb++) acc[a][bb] = (f32x4){0.f, 0.f, 0.f, 0.f};

  const int totalc = L * 2;
  for (int cc = 0; cc < totalc; ++cc) {
    __syncthreads();   // drains chunk cc staging (issued a full chunk ago)

    if (cc + 1 < totalc) {   // prefetch chunk cc+1 behind the barrier
      int nc = cc + 1;
      const u8* Bg = Mf8 + (size_t)(jt0 + (nc >> 1)) * 128 * 256 + (nc & 1) * 128;
      u8* dst = &sB8[nc & 1][0];
#pragma unroll
      for (int it = 0; it < 4; ++it) {
        int c = t + 256 * it;
        int row = c >> 3, slot = c & 7;
        int g = slot ^ (row & 7);
        async_copy16(Bg + (size_t)row * 256 + g * 16, (void*)&dst[c * 16]);
      }
    }

    const int kb = cc & 1;
    const u8* sB = &sB8[kb][0];
    i32x8 bfrag[4];
#pragma unroll
    for (int ni = 0; ni < 4; ++ni) {
      const u8* base = sB + (wn + ni * 16 + fc) * 128;
      int g0 = fr * 2;
      int4 lo = *(const int4*)(base + ((g0 ^ (fc & 7)) * 16));
      int4 hi = *(const int4*)(base + (((g0 + 1) ^ (fc & 7)) * 16));
      bfrag[ni] = (i32x8){lo.x, lo.y, lo.z, lo.w, hi.x, hi.y, hi.z, hi.w};
    }
#pragma unroll
    for (int mi = 0; mi < 4; mi++)
#pragma unroll
      for (int ni = 0; ni < 4; ni++)
        acc[mi][ni] = __builtin_amdgcn_mfma_scale_f32_16x16x128_f8f6f4(
            afr[mi][kb], bfrag[ni], acc[mi][ni], 0, 0, 0, 0x7F, 0, 0x7F);

    if (kb == 1) {
      // tile epilogue: e = exp(2*s); row partials persist; col-sums per tile
      const int j_t = jt0 + (cc >> 1);
      const int j0 = j_t * 128;
      float colp[4] = {0.f, 0.f, 0.f, 0.f};
#pragma unroll
      for (int mi = 0; mi < 4; mi++) {
#pragma unroll
        for (int ni = 0; ni < 4; ni++) {
          float e0 = __expf(acc[mi][ni][0] * INV_TAU);
          float e1 = __expf(acc[mi][ni][1] * INV_TAU);
          float e2 = __expf(acc[mi][ni][2] * INV_TAU);
          float e3 = __expf(acc[mi][ni][3] * INV_TAU);
          rowacc[mi][0] += e0; rowacc[mi][1] += e1;
          rowacc[mi][2] += e2; rowacc[mi][3] += e3;
          colp[ni] += e0 + e1 + e2 + e3;
          acc[mi][ni] = (f32x4){0.f, 0.f, 0.f, 0.f};
        }
      }
      if (j_t != i_t) {
#pragma unroll
        for (int ni = 0; ni < 4; ni++) {
          float v = colp[ni];
          v += __shfl_xor(v, 16, 64);
          v += __shfl_xor(v, 32, 64);
          if (fr == 0) atomicAdd(&rsum[j0 + wn + ni * 16 + fc], v);
        }
      }
    }
  }

  // strip-end: row-sum reduce across the 16 fc lanes, one atomic set
#pragma unroll
  for (int mi = 0; mi < 4; mi++) {
#pragma unroll
    for (int rr = 0; rr < 4; rr++) {
      float v = rowacc[mi][rr];
#pragma unroll
      for (int off = 1; off < 16; off <<= 1) v += __shfl_xor(v, off, 16);
      rowacc[mi][rr] = v;
    }
  }
  if (fc == 0) {
#pragma unroll
    for (int mi = 0; mi < 4; mi++) {
      int rbase = i0 + wm + mi * 16 + fr * 4;
      atomicAdd(&rsum[rbase + 0], rowacc[mi][0]);
      atomicAdd(&rsum[rbase + 1], rowacc[mi][1]);
      atomicAdd(&rsum[rbase + 2], rowacc[mi][2]);
      atomicAdd(&rsum[rbase + 3], rowacc[mi][3]);
    }
  }
}

// ---------------- final loss (4 rows / block), fp8 diagonal ------------------
__global__ void final_loss(const u8* __restrict__ Mf8, const float* __restrict__ rsum,
                           const float* __restrict__ snorm, float* __restrict__ out) {
  int i = blockIdx.x * 4 + (threadIdx.x >> 6);
  int lane = threadIdx.x & 63;
  unsigned int ua = ((const unsigned int*)(Mf8 + (size_t)i * 256))[lane];
  unsigned int ub = ((const unsigned int*)(Mf8 + (size_t)(Nn + i) * 256))[lane];
  float d = 0.f;
#pragma unroll
  for (int e = 0; e < 4; ++e) {
    __hip_fp8_e4m3 qa, qb;
    qa.__x = (ua >> (8 * e)) & 0xFF;
    qb.__x = (ub >> (8 * e)) & 0xFF;
    d += (float)qa * (float)qb;
  }
#pragma unroll
  for (int off = 32; off; off >>= 1) d += __shfl_xor(d, off, 64);
  if (lane == 0) {
    float den1 = rsum[i] - __expf(snorm[i] * INV_TAU);
    float den2 = rsum[Nn + i] - __expf(snorm[Nn + i] * INV_TAU);
    out[i] = 0.5f * (logf(den1) + logf(den2)) - d * INV_TAU;
  }
}

extern "C" void kernel_launch(void* const* d_in, const int* in_sizes, int n_in,
                              void* d_out, int out_size, void* d_ws, size_t ws_size,
                              hipStream_t stream) {
  const float* z1 = (const float*)d_in[0];
  const float* z2 = (const float*)d_in[1];
  const float* W1 = (const float*)d_in[2];
  const float* b1 = (const float*)d_in[3];
  const float* W2 = (const float*)d_in[4];
  const float* b2 = (const float*)d_in[5];
  float* out = (float*)d_out;

  char* ws = (char*)d_ws;
  u8*    Mf8   = (u8*)(ws);                          // 4 MB
  u16*   W1b   = (u16*)(ws + (4u << 20));            // 128 KB
  u16*   W2b   = (u16*)(ws + (4u << 20) + 131072);   // 128 KB
  float* rsum  = (float*)(ws + (4u << 20) + 262144); // 64 KB
  float* snorm = (float*)(ws + (4u << 20) + 262144 + 65536); // 64 KB

  // W pre-cast to bf16 (16384 quads each)
  wcast<<<64, 256, 0, stream>>>(W1, W2, W1b, W2b);

  // fused MLP (both layers) + normalize + fp8 emit + snorm + rsum zeroing
  mlp_norm<<<256, 256, 0, stream>>>(z1, z2, W1b, b1, W2b, b2, Mf8, snorm, rsum);

  // upper-triangle strips of <=4 tiles: 2112 blocks, long strips first
  gram_sym<<<2112, 256, 0, stream>>>(Mf8, rsum);

  final_loss<<<Nn / 4, 256, 0, stream>>>(Mf8, rsum, snorm, out);
}

// Round 11
// 177.076 us; speedup vs baseline: 1.6199x; 1.6199x over previous
//
#include <hip/hip_runtime.h>
#include <hip/hip_bf16.h>
#include <hip/hip_fp8.h>
#include <stdint.h>

#define Nn 8192
#define TWO_N 16384
#define INV_TAU 2.0f

typedef unsigned short u16;
typedef unsigned char u8;
typedef __bf16 bf16x8 __attribute__((ext_vector_type(8)));
typedef float f32x4 __attribute__((ext_vector_type(4)));
typedef int i32x8 __attribute__((ext_vector_type(8)));

typedef const __attribute__((address_space(1))) void* gas_ptr;
typedef __attribute__((address_space(3))) void* las_ptr;

__device__ __forceinline__ void async_copy16(const void* g, void* l) {
  __builtin_amdgcn_global_load_lds((gas_ptr)g, (las_ptr)l, 16, 0, 0);
}

// ---------------- fused MLP + normalize + fp8 emit ---------------------------
// 256 blocks x 64 rows. Layer1: elu(Z @ W1^T + b1) -> bf16 H1 in LDS (never
// hits HBM). Layer2: H1 @ W2^T + b2 from LDS. Then cross-wave row-norm,
// fp8 Mf8 emit, snorm = ||fp8(n)||^2, rsum zeroing. W cast inline from fp32.
__global__ __launch_bounds__(256)
void mlp_norm(const float* __restrict__ z1, const float* __restrict__ z2,
              const float* __restrict__ W1, const float* __restrict__ b1,
              const float* __restrict__ W2, const float* __restrict__ b2,
              u8* __restrict__ Mf8, float* __restrict__ snorm,
              float* __restrict__ rsum) {
  __shared__ __bf16 sZ[64 * 64];    // 8 KB  (layer1 A; reduce scratch later)
  __shared__ __bf16 sW[256 * 64];   // 32 KB (W chunk, both layers)
  __shared__ __bf16 sH[64 * 256];   // 32 KB (H1, full K for layer 2)
  const int bx = blockIdx.x;
  const int i0 = bx * 64;
  const float* Zsrc = (bx < 128) ? (z1 + (size_t)i0 * 256)
                                 : (z2 + (size_t)(i0 - Nn) * 256);
  const int t = threadIdx.x;
  const int lane = t & 63, wave = t >> 6;
  const int wn = wave * 64;
  const int fr = lane >> 4, fc = lane & 15;
  const int sw = fc & 7;

  if (t < 64) rsum[i0 + t] = 0.f;

  f32x4 acc[4][4];
#pragma unroll
  for (int a = 0; a < 4; a++)
#pragma unroll
    for (int b = 0; b < 4; b++) acc[a][b] = (f32x4){0.f, 0.f, 0.f, 0.f};

  // ---- layer 1 ----
  for (int k0 = 0; k0 < 256; k0 += 64) {
    __syncthreads();
#pragma unroll
    for (int it = 0; it < 2; ++it) {               // Z: 512 granules
      int c = t + 256 * it;
      int row = c >> 3, g = (c & 7) ^ (row & 7);
      const float* s = Zsrc + (size_t)row * 256 + k0 + g * 8;
      float4 a0 = *(const float4*)s, a1 = *(const float4*)(s + 4);
      bf16x8 v = {(__bf16)a0.x, (__bf16)a0.y, (__bf16)a0.z, (__bf16)a0.w,
                  (__bf16)a1.x, (__bf16)a1.y, (__bf16)a1.z, (__bf16)a1.w};
      *(bf16x8*)&sZ[c * 8] = v;
    }
#pragma unroll
    for (int it = 0; it < 8; ++it) {               // W1: 2048 granules
      int c = t + 256 * it;
      int row = c >> 3, g = (c & 7) ^ (row & 7);
      const float* s = W1 + (size_t)row * 256 + k0 + g * 8;
      float4 a0 = *(const float4*)s, a1 = *(const float4*)(s + 4);
      bf16x8 v = {(__bf16)a0.x, (__bf16)a0.y, (__bf16)a0.z, (__bf16)a0.w,
                  (__bf16)a1.x, (__bf16)a1.y, (__bf16)a1.z, (__bf16)a1.w};
      *(bf16x8*)&sW[c * 8] = v;
    }
    __syncthreads();
#pragma unroll
    for (int ks = 0; ks < 2; ++ks) {
      bf16x8 af[4], bfr[4];
#pragma unroll
      for (int mi = 0; mi < 4; mi++)
        af[mi] = *(const bf16x8*)&sZ[(mi * 16 + fc) * 64 + (((ks * 4 + fr) ^ sw) * 8)];
#pragma unroll
      for (int ni = 0; ni < 4; ni++)
        bfr[ni] = *(const bf16x8*)&sW[(wn + ni * 16 + fc) * 64 + (((ks * 4 + fr) ^ sw) * 8)];
#pragma unroll
      for (int mi = 0; mi < 4; mi++)
#pragma unroll
        for (int ni = 0; ni < 4; ni++)
          acc[mi][ni] = __builtin_amdgcn_mfma_f32_16x16x32_bf16(af[mi], bfr[ni], acc[mi][ni], 0, 0, 0);
    }
  }

  // layer-1 epilogue: bias + elu -> bf16 into sH (granule-xor swizzled rows)
  {
    float bv[4];
#pragma unroll
    for (int ni = 0; ni < 4; ni++) bv[ni] = b1[wn + ni * 16 + fc];
#pragma unroll
    for (int mi = 0; mi < 4; mi++)
#pragma unroll
      for (int ni = 0; ni < 4; ni++) {
        int col = wn + ni * 16 + fc;
        int gc = col >> 3;
#pragma unroll
        for (int r = 0; r < 4; r++) {
          int row = mi * 16 + fr * 4 + r;
          float v = acc[mi][ni][r] + bv[ni];
          v = v > 0.f ? v : (__expf(v) - 1.f);
          int pos = (gc & 24) | ((gc & 7) ^ (row & 7));
          sH[row * 256 + pos * 8 + (col & 7)] = (__bf16)v;
          acc[mi][ni][r] = 0.f;
        }
      }
  }

  // ---- layer 2 (A = sH, resident full-K) ----
  for (int k0 = 0; k0 < 256; k0 += 64) {
    __syncthreads();   // also guarantees: all sH writes done before first read
#pragma unroll
    for (int it = 0; it < 8; ++it) {               // W2: 2048 granules
      int c = t + 256 * it;
      int row = c >> 3, g = (c & 7) ^ (row & 7);
      const float* s = W2 + (size_t)row * 256 + k0 + g * 8;
      float4 a0 = *(const float4*)s, a1 = *(const float4*)(s + 4);
      bf16x8 v = {(__bf16)a0.x, (__bf16)a0.y, (__bf16)a0.z, (__bf16)a0.w,
                  (__bf16)a1.x, (__bf16)a1.y, (__bf16)a1.z, (__bf16)a1.w};
      *(bf16x8*)&sW[c * 8] = v;
    }
    __syncthreads();
    const int kgb = k0 >> 3;
#pragma unroll
    for (int ks = 0; ks < 2; ++ks) {
      bf16x8 af[4], bfr[4];
#pragma unroll
      for (int mi = 0; mi < 4; mi++)
        af[mi] = *(const bf16x8*)&sH[(mi * 16 + fc) * 256 + (kgb + (((ks * 4 + fr) ^ sw))) * 8];
#pragma unroll
      for (int ni = 0; ni < 4; ni++)
        bfr[ni] = *(const bf16x8*)&sW[(wn + ni * 16 + fc) * 64 + (((ks * 4 + fr) ^ sw) * 8)];
#pragma unroll
      for (int mi = 0; mi < 4; mi++)
#pragma unroll
        for (int ni = 0; ni < 4; ni++)
          acc[mi][ni] = __builtin_amdgcn_mfma_f32_16x16x32_bf16(af[mi], bfr[ni], acc[mi][ni], 0, 0, 0);
    }
  }

  // ---- epilogue: bias, cross-wave row-norm, fp8 emit, snorm ----
  float bv[4];
#pragma unroll
  for (int ni = 0; ni < 4; ni++) bv[ni] = b2[wn + ni * 16 + fc];

  __syncthreads();                 // sZ dead; reuse as reduce scratch
  float* red = (float*)sZ;         // [64 rows][4 waves]
  float* red2 = red + 256;

#pragma unroll
  for (int mi = 0; mi < 4; mi++) {
    float ssq[4] = {0.f, 0.f, 0.f, 0.f};
#pragma unroll
    for (int ni = 0; ni < 4; ni++)
#pragma unroll
      for (int r = 0; r < 4; r++) {
        float v = acc[mi][ni][r] + bv[ni];
        acc[mi][ni][r] = v;
        ssq[r] += v * v;
      }
#pragma unroll
    for (int r = 0; r < 4; r++) {
      float v = ssq[r];
#pragma unroll
      for (int off = 1; off < 16; off <<= 1) v += __shfl_xor(v, off, 16);
      if (fc == 0) red[(mi * 16 + fr * 4 + r) * 4 + wave] = v;
    }
  }
  __syncthreads();

#pragma unroll
  for (int mi = 0; mi < 4; mi++) {
    float ssq2[4] = {0.f, 0.f, 0.f, 0.f};
#pragma unroll
    for (int r = 0; r < 4; r++) {
      int row = mi * 16 + fr * 4 + r;
      float ss = red[row * 4] + red[row * 4 + 1] + red[row * 4 + 2] + red[row * 4 + 3];
      float rn = 1.f / fmaxf(sqrtf(ss), 1e-12f);
#pragma unroll
      for (int ni = 0; ni < 4; ni++) {
        float v = acc[mi][ni][r] * rn;
        __hip_fp8_e4m3 q(v);
        Mf8[(size_t)(i0 + row) * 256 + wn + ni * 16 + fc] = q.__x;
        float fv = (float)q;
        ssq2[r] += fv * fv;
      }
    }
#pragma unroll
    for (int r = 0; r < 4; r++) {
      float v = ssq2[r];
#pragma unroll
      for (int off = 1; off < 16; off <<= 1) v += __shfl_xor(v, off, 16);
      if (fc == 0) red2[(mi * 16 + fr * 4 + r) * 4 + wave] = v;
    }
  }
  __syncthreads();
  if (t < 64)
    snorm[i0 + t] = red2[t * 4] + red2[t * 4 + 1] + red2[t * 4 + 2] + red2[t * 4 + 3];
}

// ---------------- symmetric Gram, MX fp8 K=128, A-in-regs, B dbuf ------------
// Round-9 proven version: 2 x 32 KB B dbuf, one barrier per tile, prefetch
// issued behind the barrier; A fragments persistent in registers per strip.
// NOTE: acc lives in AGPRs (unified file); do NOT force min-occupancy >2 —
// the ~190-reg unified footprint spills catastrophically (round-10 lesson).
__global__ __launch_bounds__(256, 2)
void gram_sym(const u8* __restrict__ Mf8, float* __restrict__ rsum) {
  __shared__ u8 sB8[2][128 * 256];   // 2 x 32 KB
  const int t = threadIdx.x;
  const int lane = t & 63, wave = t >> 6;
  const int wm = (wave >> 1) * 64, wn = (wave & 1) * 64;
  const int fr = lane >> 4, fc = lane & 15;

  // ---- strip mapping (band closed form), long strips dispatched first ----
  int f = 2111 - blockIdx.x;
  int b = 0;
  while (f >= 2 * (b + 1) * (b + 2)) ++b;
  int rem = f - 2 * b * (b + 1);
  int r = rem / (b + 1);
  int q = rem - r * (b + 1);
  int k = 4 * b + 1 + r;
  const int i_t = 128 - k;
  const int jt0 = i_t + 4 * q;
  const int L = min(4, k - 4 * q);
  const int i0 = i_t * 128;

  // stage B(tile 0) into buffer 0
  {
    const u8* Bg = Mf8 + (size_t)jt0 * 128 * 256;
#pragma unroll
    for (int it = 0; it < 8; ++it) {
      int c = t + 256 * it;
      int row = c >> 4, slot = c & 15;
      int g = slot ^ (row & 15);
      async_copy16(Bg + (size_t)row * 256 + g * 16, (void*)&sB8[0][c * 16]);
    }
  }

  // gather A fragments into registers (L2/L3-resident; once per strip)
  i32x8 afr[4][2];
  {
    const u8* Ag = Mf8 + (size_t)i0 * 256;
#pragma unroll
    for (int mi = 0; mi < 4; ++mi) {
      const u8* rp = Ag + (size_t)(wm + mi * 16 + fc) * 256 + fr * 32;
#pragma unroll
      for (int kb = 0; kb < 2; ++kb) {
        int4 lo = *(const int4*)(rp + kb * 128);
        int4 hi = *(const int4*)(rp + kb * 128 + 16);
        afr[mi][kb] = (i32x8){lo.x, lo.y, lo.z, lo.w, hi.x, hi.y, hi.z, hi.w};
      }
    }
  }

  float rowacc[4][4];
#pragma unroll
  for (int a = 0; a < 4; a++)
#pragma unroll
    for (int rr = 0; rr < 4; rr++) rowacc[a][rr] = 0.f;

  for (int jt = 0; jt < L; ++jt) {
    const int j_t = jt0 + jt;
    const int j0 = j_t * 128;
    const u8* sB = &sB8[jt & 1][0];

    __syncthreads();   // drains B(jt) staging (issued >=1 tile ago; landed)

    if (jt + 1 < L) {  // prefetch B(jt+1) behind the barrier
      const u8* Bg = Mf8 + (size_t)(j_t + 1) * 128 * 256;
      u8* dst = &sB8[(jt + 1) & 1][0];
#pragma unroll
      for (int it = 0; it < 8; ++it) {
        int c = t + 256 * it;
        int row = c >> 4, slot = c & 15;
        int g = slot ^ (row & 15);
        async_copy16(Bg + (size_t)row * 256 + g * 16, (void*)&dst[c * 16]);
      }
    }

    f32x4 acc[4][4];
#pragma unroll
    for (int a = 0; a < 4; a++)
#pragma unroll
      for (int bb = 0; bb < 4; bb++) acc[a][bb] = (f32x4){0.f, 0.f, 0.f, 0.f};

#pragma unroll
    for (int kb = 0; kb < 2; ++kb) {
      i32x8 bfrag[4];
#pragma unroll
      for (int ni = 0; ni < 4; ++ni) {
        const u8* base = sB + (wn + ni * 16 + fc) * 256;
        int g0 = kb * 8 + fr * 2;
        int4 lo = *(const int4*)(base + ((g0 ^ fc) * 16));
        int4 hi = *(const int4*)(base + (((g0 + 1) ^ fc) * 16));
        bfrag[ni] = (i32x8){lo.x, lo.y, lo.z, lo.w, hi.x, hi.y, hi.z, hi.w};
      }
#pragma unroll
      for (int mi = 0; mi < 4; mi++)
#pragma unroll
        for (int ni = 0; ni < 4; ni++)
          acc[mi][ni] = __builtin_amdgcn_mfma_scale_f32_16x16x128_f8f6f4(
              afr[mi][kb], bfrag[ni], acc[mi][ni], 0, 0, 0, 0x7F, 0, 0x7F);
    }

    // tile epilogue
    float colp[4] = {0.f, 0.f, 0.f, 0.f};
#pragma unroll
    for (int mi = 0; mi < 4; mi++) {
#pragma unroll
      for (int ni = 0; ni < 4; ni++) {
        float e0 = __expf(acc[mi][ni][0] * INV_TAU);
        float e1 = __expf(acc[mi][ni][1] * INV_TAU);
        float e2 = __expf(acc[mi][ni][2] * INV_TAU);
        float e3 = __expf(acc[mi][ni][3] * INV_TAU);
        rowacc[mi][0] += e0; rowacc[mi][1] += e1;
        rowacc[mi][2] += e2; rowacc[mi][3] += e3;
        colp[ni] += e0 + e1 + e2 + e3;
      }
    }
    if (j_t != i_t) {
#pragma unroll
      for (int ni = 0; ni < 4; ni++) {
        float v = colp[ni];
        v += __shfl_xor(v, 16, 64);
        v += __shfl_xor(v, 32, 64);
        if (fr == 0) atomicAdd(&rsum[j0 + wn + ni * 16 + fc], v);
      }
    }
  }

  // strip-end: row-sum reduce across the 16 fc lanes, one atomic set
#pragma unroll
  for (int mi = 0; mi < 4; mi++) {
#pragma unroll
    for (int rr = 0; rr < 4; rr++) {
      float v = rowacc[mi][rr];
#pragma unroll
      for (int off = 1; off < 16; off <<= 1) v += __shfl_xor(v, off, 16);
      rowacc[mi][rr] = v;
    }
  }
  if (fc == 0) {
#pragma unroll
    for (int mi = 0; mi < 4; mi++) {
      int rbase = i0 + wm + mi * 16 + fr * 4;
      atomicAdd(&rsum[rbase + 0], rowacc[mi][0]);
      atomicAdd(&rsum[rbase + 1], rowacc[mi][1]);
      atomicAdd(&rsum[rbase + 2], rowacc[mi][2]);
      atomicAdd(&rsum[rbase + 3], rowacc[mi][3]);
    }
  }
}

// ---------------- final loss (4 rows / block), fp8 diagonal ------------------
__global__ void final_loss(const u8* __restrict__ Mf8, const float* __restrict__ rsum,
                           const float* __restrict__ snorm, float* __restrict__ out) {
  int i = blockIdx.x * 4 + (threadIdx.x >> 6);
  int lane = threadIdx.x & 63;
  unsigned int ua = ((const unsigned int*)(Mf8 + (size_t)i * 256))[lane];
  unsigned int ub = ((const unsigned int*)(Mf8 + (size_t)(Nn + i) * 256))[lane];
  float d = 0.f;
#pragma unroll
  for (int e = 0; e < 4; ++e) {
    __hip_fp8_e4m3 qa, qb;
    qa.__x = (ua >> (8 * e)) & 0xFF;
    qb.__x = (ub >> (8 * e)) & 0xFF;
    d += (float)qa * (float)qb;
  }
#pragma unroll
  for (int off = 32; off; off >>= 1) d += __shfl_xor(d, off, 64);
  if (lane == 0) {
    float den1 = rsum[i] - __expf(snorm[i] * INV_TAU);
    float den2 = rsum[Nn + i] - __expf(snorm[Nn + i] * INV_TAU);
    out[i] = 0.5f * (logf(den1) + logf(den2)) - d * INV_TAU;
  }
}

extern "C" void kernel_launch(void* const* d_in, const int* in_sizes, int n_in,
                              void* d_out, int out_size, void* d_ws, size_t ws_size,
                              hipStream_t stream) {
  const float* z1 = (const float*)d_in[0];
  const float* z2 = (const float*)d_in[1];
  const float* W1 = (const float*)d_in[2];
  const float* b1 = (const float*)d_in[3];
  const float* W2 = (const float*)d_in[4];
  const float* b2 = (const float*)d_in[5];
  float* out = (float*)d_out;

  char* ws = (char*)d_ws;
  u8*    Mf8   = (u8*)(ws);                          // 4 MB
  float* rsum  = (float*)(ws + (4u << 20));          // 64 KB
  float* snorm = (float*)(ws + (4u << 20) + 65536);  // 64 KB

  // fused MLP (both layers) + normalize + fp8 emit + snorm + rsum zeroing
  mlp_norm<<<256, 256, 0, stream>>>(z1, z2, W1, b1, W2, b2, Mf8, snorm, rsum);

  // upper-triangle strips of <=4 tiles: 2112 blocks, long strips first
  gram_sym<<<2112, 256, 0, stream>>>(Mf8, rsum);

  final_loss<<<Nn / 4, 256, 0, stream>>>(Mf8, rsum, snorm, out);
}